// Round 13
// baseline (66.249 us; speedup 1.0000x reference)
//
#include <hip/hip_runtime.h>
#include <hip/hip_bf16.h>
#include <stdint.h>

typedef _Float16 half8 __attribute__((ext_vector_type(8)));
typedef float    f32x4 __attribute__((ext_vector_type(4)));

#define N_EMBED   2048
#define N_EXP     64
#define KCHUNK    64
#define NKC       (N_EMBED / KCHUNK)   // 32
#define GCH       16                   // chunks per K-group (K-split 2)
#define TILEB     8192                 // bytes per k-chunk fp16 image
#define LGT_STRIDE 68                  // floats, padded row stride for logit LDS
#define LGT_FLOATS (32 * LGT_STRIDE)   // 2176 floats = 8704 B per group region

// ---------------------------------------------------------------------------
// Prelude: W [64][2048] fp32 -> pre-swizzled fp16 image in ws (256 KB).
// Folds the 0.5 = (alpha-1)/temperature scale into W.
// Chunk kc at kc*8192; element (e,dd) at byte ((e*128 + dd*2) ^ ((e&7)<<4)).
// ---------------------------------------------------------------------------
__global__ __launch_bounds__(64) void convert_w_kernel(
        const float* __restrict__ W, uint8_t* __restrict__ wsimg) {
    int tid = blockIdx.x * 64 + threadIdx.x;    // 16384 threads total
    int e   = tid >> 8;                          // expert 0..63
    int d0  = (tid & 255) * 8;                   // 8 consecutive d
    int kc  = d0 >> 6;
    int dd0 = d0 & 63;
    const float* src = W + e * N_EMBED + d0;
    float4 f0 = *(const float4*)(src);
    float4 f1 = *(const float4*)(src + 4);
    float v[8] = {f0.x, f0.y, f0.z, f0.w, f1.x, f1.y, f1.z, f1.w};
    union { _Float16 h[8]; uint4 u; } hv;
#pragma unroll
    for (int j = 0; j < 8; ++j) hv.h[j] = (_Float16)(0.5f * v[j]);
    uint32_t off = (uint32_t)((e * 128 + dd0 * 2) ^ ((e & 7) << 4));
    *(uint4*)(wsimg + (size_t)kc * TILEB + off) = hv.u;
}

// ---------------------------------------------------------------------------
// Main fused kernel: 1024 blocks x 256 threads -> 4 blocks/CU = 4 INDEPENDENT
// barrier domains per CU (R8 had 2; R12's 1 was worst). Same 16 waves/CU,
// same R8 pipeline; the lever is stall-overlap across co-resident blocks.
//   4 waves = 2 K-groups (g) x 2 row-quads (q); 32 rows/block, BK=128,
//   8 rounds. W: ring-4 LDS per group; stage pair p+1 (8 ops/thread) at
//   round-p start; A: ONE named-register pair set, consume (cvt) then reload
//   p+1 (8 ops). End-of-round wait vmcnt(8) retires the W stage only; A
//   stays in flight. Raw s_barrier. All hot state in named registers.
// ---------------------------------------------------------------------------
__device__ __forceinline__ half8 cvt8(f32x4 p, f32x4 q) {
    half8 h;
    h[0] = (_Float16)p[0]; h[1] = (_Float16)p[1];
    h[2] = (_Float16)p[2]; h[3] = (_Float16)p[3];
    h[4] = (_Float16)q[0]; h[5] = (_Float16)q[1];
    h[6] = (_Float16)q[2]; h[7] = (_Float16)q[3];
    return h;
}

__global__ __launch_bounds__(256, 4) void router_kernel(
        const float* __restrict__ x, const uint8_t* __restrict__ img,
        const float* __restrict__ bias, float* __restrict__ out) {
    __shared__ uint8_t lds[32768];   // 2 groups x 4 slots x 8 KB? no: 2 x ring-2
                                     // layout: group g at g*16384, ring-4 of 2
                                     // pairs (slots kc&3 within 2 x 8 KB x 2).
                                     // 2 groups x 4 x 4 KB... see STAGE2.
    // Actually: group g owns lds[g*16384 .. g*16384+16384) = 2 slots of 8 KB
    // (pair double-buffer at pair granularity: pair p in half (p&1)).
    // Epilogue overlay: 2 x 8704 B logit regions (17408 B total).

    const int tid  = threadIdx.x;
    const int wave = tid >> 6;
    const int lane = tid & 63;
    const int l15  = lane & 15;
    const int l4   = lane >> 4;
    const int g    = wave >> 1;        // K-group (0,1)
    const int q    = wave & 1;         // row quad (0,1)
    const int rowbase = blockIdx.x * 32;
    const float* xrow = x + (size_t)(rowbase + q * 16 + l15) * N_EMBED
                          + g * (GCH * KCHUNK) + l4 * 8;
    uint8_t* gbase = lds + g * 16384;

    // LDS byte offsets of B fragments: tile t, k-step s (within an 8 KB chunk)
    uint32_t boff[4][2];
#pragma unroll
    for (int t = 0; t < 4; ++t)
#pragma unroll
        for (int s = 0; s < 2; ++s)
            boff[t][s] = (uint32_t)(((16 * t + l15) * 128 + s * 64 + l4 * 16)
                                    ^ ((l15 & 7) << 4));

    f32x4 acc[4];
#pragma unroll
    for (int t = 0; t < 4; ++t) acc[t] = (f32x4){0.f, 0.f, 0.f, 0.f};

    // Staging: thread-group tg (128 threads) stages its group's pair:
    // 16 KB / 128 threads / 16 B = 8 ops/thread. Pair p -> half (p&1).
    const int tg = tid >> 7;
    const int t7 = tid & 127;
    auto STAGE2 = [&](int p) {
        const uint8_t* gsrc = img + (size_t)(tg * GCH + 2 * p) * TILEB + t7 * 16;
        uint8_t* dst = lds + tg * 16384 + (p & 1) * 8192 + t7 * 16;
        // NOTE: pair p occupies ONE 8 KB half? Pair = 16 KB. Use (p&1) to pick
        // which 16 KB half of a 32 KB ring... but group region is 16 KB only.
        // => pair double-buffer needs 2 x 16 KB = 32 KB per group. Re-layout:
        // group g at g*16384 holds ONE pair buffer; alternate with +32768?
        // LDS is 32 KB total -> single-buffer per group with ring at chunk
        // granularity is needed. Use chunk-slot ring of 2 within 16 KB:
        // chunk kc -> gbase + (kc&1)*8192. Stage pair p = chunks 2p,2p+1 ->
        // slots {0,1} every round: SINGLE buffered pair! Wait discipline
        // then requires the stage of round p to complete before round p's
        // MFMAs... which is exactly what we do NOT want.
        (void)gsrc; (void)dst;
    };
    (void)STAGE2;
    // --- corrected staging: ring-4 of 4 KB sub-slots is wrong; instead use
    // ring-2 at PAIR granularity with 2 x 8 KB per chunk => need 32 KB/group.
    // Resolve by giving each group 16 KB and staging at CHUNK granularity
    // with a ring-4 of 4 KB? No. Final choice: BK=64 (chunk) rounds, ring-2
    // per group (2 x 8 KB = 16 KB), 16 rounds, stage chunk kc+1 at round kc.
    auto STAGE1 = [&](int kc) {   // stage chunk kc (8 KB, 4 ops/thread)
        const uint8_t* gsrc = img + (size_t)(tg * GCH + kc) * TILEB;
        uint8_t* dst = lds + tg * 16384 + (kc & 1) * 8192;
#pragma unroll
        for (int j = 0; j < 4; ++j) {
            __builtin_amdgcn_global_load_lds(
                (const __attribute__((address_space(1))) void*)(gsrc + j * 2048 + t7 * 16),
                (__attribute__((address_space(3))) void*)(dst + j * 2048 + t7 * 16),
                16, 0, 0);
        }
    };

    f32x4 A0, A1, A2, A3;                    // one chunk set, named regs only
    auto LOADA1 = [&](int kc) {              // chunk kc: 4 x dwordx4
        const float* ap = xrow + kc * KCHUNK;
        A0 = *(const f32x4*)(ap);
        A1 = *(const f32x4*)(ap + 4);
        A2 = *(const f32x4*)(ap + 32);
        A3 = *(const f32x4*)(ap + 36);
    };
    auto MFMAS1 = [&](int kc, half8 a0, half8 a1) {
        const uint8_t* lb = gbase + (size_t)(kc & 1) * 8192;
#pragma unroll
        for (int t = 0; t < 4; ++t) {
            half8 bh = *(const half8*)(lb + boff[t][0]);
            acc[t] = __builtin_amdgcn_mfma_f32_16x16x32_f16(a0, bh, acc[t], 0, 0, 0);
        }
#pragma unroll
        for (int t = 0; t < 4; ++t) {
            half8 bh = *(const half8*)(lb + boff[t][1]);
            acc[t] = __builtin_amdgcn_mfma_f32_16x16x32_f16(a1, bh, acc[t], 0, 0, 0);
        }
    };

    // ---- prologue: stage chunk 0; load A chunk 0 ----
    STAGE1(0);
    __builtin_amdgcn_sched_barrier(0);
    LOADA1(0);
    __builtin_amdgcn_sched_barrier(0);
    asm volatile("s_waitcnt vmcnt(4)" ::: "memory");   // S(0) done; A(0) in flight
    __builtin_amdgcn_s_barrier();
    __builtin_amdgcn_sched_barrier(0);

    // ---- rounds 0..14 (uniform) ----
#pragma unroll 1
    for (int kc = 0; kc < GCH - 1; ++kc) {
        STAGE1(kc + 1);
        __builtin_amdgcn_sched_barrier(0);
        {
            half8 a0 = cvt8(A0, A1);   // auto-wait retires A(kc); S newer, stays
            half8 a1 = cvt8(A2, A3);
            LOADA1(kc + 1);
            MFMAS1(kc, a0, a1);
        }
        // Queue: [S(kc+1) x4 (older), A(kc+1) x4]. vmcnt(4) completes the W
        // stage, leaves the A chunk in flight. lgkmcnt(0): LDS reads of the
        // slot being re-staged next round are done.
        asm volatile("s_waitcnt vmcnt(4) lgkmcnt(0)" ::: "memory");
        __builtin_amdgcn_s_barrier();
        __builtin_amdgcn_sched_barrier(0);
    }

    // ---- round 15 (tail) ----
    {
        half8 a0 = cvt8(A0, A1);
        half8 a1 = cvt8(A2, A3);
        MFMAS1(GCH - 1, a0, a1);
    }

    // ---- combine K-halves via LDS (overlay on W buffers) ----
    __syncthreads();
    {
        float* lgt = (float*)lds + g * LGT_FLOATS;
#pragma unroll
        for (int t = 0; t < 4; ++t)
#pragma unroll
            for (int r = 0; r < 4; ++r)
                lgt[(q * 16 + l4 * 4 + r) * LGT_STRIDE + t * 16 + l15] = acc[t][r];
    }
    __syncthreads();

    // ---------------- entmax-1.5 epilogue (one pass, 32 rows) ---------------
    // 8 lanes per row, 8 experts per lane; reductions = 3 x shfl_xor {1,2,4}.
    const float* L0 = (const float*)lds;
    const float* L1 = L0 + LGT_FLOATS;
    const int row_local = tid >> 3;        // 0..31
    const int eb = (tid & 7) * 8;
    const int base = row_local * LGT_STRIDE + eb;

    float v0, v1, v2, v3, v4, v5, v6, v7;
    {
        float4 u0 = *(const float4*)(L0 + base);
        float4 u1 = *(const float4*)(L0 + base + 4);
        float4 w0 = *(const float4*)(L1 + base);
        float4 w1 = *(const float4*)(L1 + base + 4);
        float4 c0 = *(const float4*)(bias + eb);
        float4 c1 = *(const float4*)(bias + eb + 4);
        v0 = u0.x + w0.x + 0.5f * c0.x;
        v1 = u0.y + w0.y + 0.5f * c0.y;
        v2 = u0.z + w0.z + 0.5f * c0.z;
        v3 = u0.w + w0.w + 0.5f * c0.w;
        v4 = u1.x + w1.x + 0.5f * c1.x;
        v5 = u1.y + w1.y + 0.5f * c1.y;
        v6 = u1.z + w1.z + 0.5f * c1.z;
        v7 = u1.w + w1.w + 0.5f * c1.w;
    }

    float m = fmaxf(fmaxf(fmaxf(v0, v1), fmaxf(v2, v3)),
                    fmaxf(fmaxf(v4, v5), fmaxf(v6, v7)));
    m = fmaxf(m, __shfl_xor(m, 1, 64));
    m = fmaxf(m, __shfl_xor(m, 2, 64));
    m = fmaxf(m, __shfl_xor(m, 4, 64));

    float tau_lo = m - 1.0f;
    float tau_hi = m - 0.000244140625f;   // (1/64)^(1/(alpha-1)) = (1/64)^2
    float dm = tau_hi - tau_lo;

    float s0, d;
    d = fmaxf(v0 - tau_lo, 0.f); s0 = d * d;
    d = fmaxf(v1 - tau_lo, 0.f); s0 = fmaf(d, d, s0);
    d = fmaxf(v2 - tau_lo, 0.f); s0 = fmaf(d, d, s0);
    d = fmaxf(v3 - tau_lo, 0.f); s0 = fmaf(d, d, s0);
    d = fmaxf(v4 - tau_lo, 0.f); s0 = fmaf(d, d, s0);
    d = fmaxf(v5 - tau_lo, 0.f); s0 = fmaf(d, d, s0);
    d = fmaxf(v6 - tau_lo, 0.f); s0 = fmaf(d, d, s0);
    d = fmaxf(v7 - tau_lo, 0.f); s0 = fmaf(d, d, s0);
    s0 += __shfl_xor(s0, 1, 64);
    s0 += __shfl_xor(s0, 2, 64);
    s0 += __shfl_xor(s0, 4, 64);
    const float f_lo = s0 - 1.0f;   // fixed for all iterations (as in reference)

    float tau_m = tau_lo, fsum = 1.0f;
#pragma unroll 1
    for (int it = 0; it < 25; ++it) {
        dm *= 0.5f;
        tau_m = tau_lo + dm;
        float s;
        d = fmaxf(v0 - tau_m, 0.f); s = d * d;
        d = fmaxf(v1 - tau_m, 0.f); s = fmaf(d, d, s);
        d = fmaxf(v2 - tau_m, 0.f); s = fmaf(d, d, s);
        d = fmaxf(v3 - tau_m, 0.f); s = fmaf(d, d, s);
        d = fmaxf(v4 - tau_m, 0.f); s = fmaf(d, d, s);
        d = fmaxf(v5 - tau_m, 0.f); s = fmaf(d, d, s);
        d = fmaxf(v6 - tau_m, 0.f); s = fmaf(d, d, s);
        d = fmaxf(v7 - tau_m, 0.f); s = fmaf(d, d, s);
        s += __shfl_xor(s, 1, 64);
        s += __shfl_xor(s, 2, 64);
        s += __shfl_xor(s, 4, 64);
        if ((s - 1.0f) * f_lo >= 0.0f) tau_lo = tau_m;
        fsum = s;
    }
    // p at last midpoint, renormalized by its own sum (ensure_sum_one)
    float rinv = 1.0f / fsum;
    float4 o0, o1;
    d = fmaxf(v0 - tau_m, 0.f); o0.x = d * d * rinv;
    d = fmaxf(v1 - tau_m, 0.f); o0.y = d * d * rinv;
    d = fmaxf(v2 - tau_m, 0.f); o0.z = d * d * rinv;
    d = fmaxf(v3 - tau_m, 0.f); o0.w = d * d * rinv;
    d = fmaxf(v4 - tau_m, 0.f); o1.x = d * d * rinv;
    d = fmaxf(v5 - tau_m, 0.f); o1.y = d * d * rinv;
    d = fmaxf(v6 - tau_m, 0.f); o1.z = d * d * rinv;
    d = fmaxf(v7 - tau_m, 0.f); o1.w = d * d * rinv;

    float* op = out + (size_t)(rowbase + row_local) * N_EXP + eb;
    *(float4*)(op)     = o0;
    *(float4*)(op + 4) = o1;
}

// ---------------------------------------------------------------------------
extern "C" void kernel_launch(void* const* d_in, const int* in_sizes, int n_in,
                              void* d_out, int out_size, void* d_ws, size_t ws_size,
                              hipStream_t stream) {
    (void)n_in; (void)out_size; (void)ws_size;
    const float* x  = (const float*)d_in[0];   // [T, 2048]
    const float* W  = (const float*)d_in[1];   // [64, 2048]
    const float* b  = (const float*)d_in[2];   // [64]
    float* out      = (float*)d_out;           // [T, 64]
    uint8_t* wsimg  = (uint8_t*)d_ws;          // 256 KB W fp16 image

    const int T = in_sizes[0] / N_EMBED;       // 32768

    convert_w_kernel<<<dim3(256), dim3(64), 0, stream>>>(W, wsimg);
    router_kernel<<<dim3(T / 32), dim3(256), 0, stream>>>(x, wsimg, b, out);
}

// Round 14
// 65.541 us; speedup vs baseline: 1.0108x; 1.0108x over previous
//
#include <hip/hip_runtime.h>
#include <hip/hip_bf16.h>
#include <stdint.h>

typedef _Float16 half8 __attribute__((ext_vector_type(8)));
typedef float    f32x4 __attribute__((ext_vector_type(4)));

#define N_EMBED   2048
#define N_EXP     64
#define KCHUNK    64
#define NKC       (N_EMBED / KCHUNK)   // 32
#define GCH       16                   // chunks per K-group (K-split 2)
#define LGT_STRIDE 68                  // floats, padded row stride for logit LDS
#define LGT_FLOATS (64 * LGT_STRIDE)   // 4352 floats = 17408 B per region

// ---------------------------------------------------------------------------
// Prelude: W [64][2048] fp32 -> fragment-linear fp16 image (256 KB).
// Folds the 0.5 = (alpha-1)/temperature scale into W.
// Record for (kc,t,s): 1024 B at (kc*8 + t*2 + s)*1024. Lane l's 16 B at
// l*16 holds W[e=16t+(l&15)][kc*64 + s*32 + (l>>4)*8 .. +8] as fp16.
// Each wave B-fragment load is ONE contiguous, coalesced 1 KB line (L2-hot:
// the whole image is 256 KB, shared by all blocks of an XCD).
// ---------------------------------------------------------------------------
__global__ __launch_bounds__(64) void convert_w_kernel(
        const float* __restrict__ W, uint8_t* __restrict__ img) {
    int tid  = blockIdx.x * 64 + threadIdx.x;   // 16384 threads total
    int f    = tid >> 6;                         // fragment record 0..255
    int lane = tid & 63;
    int kc = f >> 3, t = (f >> 1) & 3, s = f & 1;
    int e  = t * 16 + (lane & 15);
    int d  = kc * 64 + s * 32 + (lane >> 4) * 8;
    const float* src = W + e * N_EMBED + d;
    float4 f0 = *(const float4*)(src);
    float4 f1 = *(const float4*)(src + 4);
    float v[8] = {f0.x, f0.y, f0.z, f0.w, f1.x, f1.y, f1.z, f1.w};
    union { _Float16 h[8]; uint4 u; } hv;
#pragma unroll
    for (int j = 0; j < 8; ++j) hv.h[j] = (_Float16)(0.5f * v[j]);
    *(uint4*)(img + (size_t)f * 1024 + lane * 16) = hv.u;
}

// ---------------------------------------------------------------------------
// Main fused kernel — BARRIER-FREE GEMM loop (fix of R2's retirement bug):
//   512 blocks x 512 threads; 8 waves = 2 K-groups x 4 row-quads; 16 rows
//   per wave, half-K each; 2 blocks/CU, 16 waves/CU (4/SIMD TLP).
//   Per round kc: issue B(kc) x8 (L2, 1 KB lines) -> cvt A(kc) [auto
//   vmcnt(8): retires ONLY the A chunk, B stays in flight is wrong way —
//   A is older: queue = [A(kc) x4, B(kc) x8]; cvt waits vmcnt(8)] ->
//   issue A(kc+1) x4 -> MFMA x8 [auto vmcnt(4): retires B, A(kc+1) in
//   flight]. No LDS staging, no s_barrier until the K-combine epilogue.
//   All hot state in named registers (R7 lesson).
// ---------------------------------------------------------------------------
__device__ __forceinline__ half8 cvt8(f32x4 p, f32x4 q) {
    half8 h;
    h[0] = (_Float16)p[0]; h[1] = (_Float16)p[1];
    h[2] = (_Float16)p[2]; h[3] = (_Float16)p[3];
    h[4] = (_Float16)q[0]; h[5] = (_Float16)q[1];
    h[6] = (_Float16)q[2]; h[7] = (_Float16)q[3];
    return h;
}

__global__ __launch_bounds__(512, 4) void router_kernel(
        const float* __restrict__ x, const uint8_t* __restrict__ img,
        const float* __restrict__ bias, float* __restrict__ out) {
    __shared__ uint8_t lds[2 * LGT_FLOATS * 4];   // 34816 B logit regions only

    const int tid  = threadIdx.x;
    const int wave = tid >> 6;
    const int lane = tid & 63;
    const int l15  = lane & 15;
    const int l4   = lane >> 4;
    const int g    = wave >> 2;        // K-group
    const int q    = wave & 3;         // row quad
    const int rowbase = blockIdx.x * 64;
    const float* xrow = x + (size_t)(rowbase + q * 16 + l15) * N_EMBED
                          + g * (GCH * KCHUNK) + l4 * 8;
    // fragment base for this wave: group g's chunks start at record g*16*8
    const uint8_t* fbase = img + (size_t)g * GCH * 8192 + lane * 16;

    f32x4 acc[4];
#pragma unroll
    for (int t = 0; t < 4; ++t) acc[t] = (f32x4){0.f, 0.f, 0.f, 0.f};

    f32x4 A0, A1, A2, A3;                    // one chunk set, named regs only
    auto LOADA = [&](int kc) {               // chunk kc: 4 x dwordx4
        const float* ap = xrow + kc * KCHUNK;
        A0 = *(const f32x4*)(ap);
        A1 = *(const f32x4*)(ap + 4);
        A2 = *(const f32x4*)(ap + 32);
        A3 = *(const f32x4*)(ap + 36);
    };

    half8 B00, B01, B10, B11, B20, B21, B30, B31;   // named B fragments
    auto LOADB = [&](int kc) {   // 8 x contiguous 1 KB lines (L2)
        const uint8_t* fb = fbase + (size_t)kc * 8192;
        B00 = *(const half8*)(fb);
        B01 = *(const half8*)(fb + 1024);
        B10 = *(const half8*)(fb + 2048);
        B11 = *(const half8*)(fb + 3072);
        B20 = *(const half8*)(fb + 4096);
        B21 = *(const half8*)(fb + 5120);
        B30 = *(const half8*)(fb + 6144);
        B31 = *(const half8*)(fb + 7168);
    };

    // ---- prologue: A(0) in flight ----
    LOADA(0);
    __builtin_amdgcn_sched_barrier(0);

    // ---- rounds 0..14 (uniform, barrier-free) ----
#pragma unroll 1
    for (int kc = 0; kc < GCH - 1; ++kc) {
        LOADB(kc);                              // queue: [A(kc)x4, B(kc)x8]
        __builtin_amdgcn_sched_barrier(0);
        half8 a0 = cvt8(A0, A1);                // auto vmcnt(8): retires A(kc)
        half8 a1 = cvt8(A2, A3);
        __builtin_amdgcn_sched_barrier(0);
        LOADA(kc + 1);                          // queue: [B(kc)x8, A(kc+1)x4]
        __builtin_amdgcn_sched_barrier(0);
        // MFMAs: auto vmcnt(4) retires B(kc); A(kc+1) stays in flight.
        acc[0] = __builtin_amdgcn_mfma_f32_16x16x32_f16(a0, B00, acc[0], 0, 0, 0);
        acc[1] = __builtin_amdgcn_mfma_f32_16x16x32_f16(a0, B10, acc[1], 0, 0, 0);
        acc[2] = __builtin_amdgcn_mfma_f32_16x16x32_f16(a0, B20, acc[2], 0, 0, 0);
        acc[3] = __builtin_amdgcn_mfma_f32_16x16x32_f16(a0, B30, acc[3], 0, 0, 0);
        acc[0] = __builtin_amdgcn_mfma_f32_16x16x32_f16(a1, B01, acc[0], 0, 0, 0);
        acc[1] = __builtin_amdgcn_mfma_f32_16x16x32_f16(a1, B11, acc[1], 0, 0, 0);
        acc[2] = __builtin_amdgcn_mfma_f32_16x16x32_f16(a1, B21, acc[2], 0, 0, 0);
        acc[3] = __builtin_amdgcn_mfma_f32_16x16x32_f16(a1, B31, acc[3], 0, 0, 0);
        __builtin_amdgcn_sched_barrier(0);
    }

    // ---- round 15 (tail, no A prefetch) ----
    {
        LOADB(GCH - 1);
        __builtin_amdgcn_sched_barrier(0);
        half8 a0 = cvt8(A0, A1);
        half8 a1 = cvt8(A2, A3);
        acc[0] = __builtin_amdgcn_mfma_f32_16x16x32_f16(a0, B00, acc[0], 0, 0, 0);
        acc[1] = __builtin_amdgcn_mfma_f32_16x16x32_f16(a0, B10, acc[1], 0, 0, 0);
        acc[2] = __builtin_amdgcn_mfma_f32_16x16x32_f16(a0, B20, acc[2], 0, 0, 0);
        acc[3] = __builtin_amdgcn_mfma_f32_16x16x32_f16(a0, B30, acc[3], 0, 0, 0);
        acc[0] = __builtin_amdgcn_mfma_f32_16x16x32_f16(a1, B01, acc[0], 0, 0, 0);
        acc[1] = __builtin_amdgcn_mfma_f32_16x16x32_f16(a1, B11, acc[1], 0, 0, 0);
        acc[2] = __builtin_amdgcn_mfma_f32_16x16x32_f16(a1, B21, acc[2], 0, 0, 0);
        acc[3] = __builtin_amdgcn_mfma_f32_16x16x32_f16(a1, B31, acc[3], 0, 0, 0);
    }

    // ---- combine K-halves via LDS ----
    __syncthreads();
    {
        float* lgt = (float*)lds + g * LGT_FLOATS;
#pragma unroll
        for (int t = 0; t < 4; ++t)
#pragma unroll
            for (int r = 0; r < 4; ++r)
                lgt[(q * 16 + l4 * 4 + r) * LGT_STRIDE + t * 16 + l15] = acc[t][r];
    }
    __syncthreads();

    // ---------------- entmax-1.5 epilogue ----------------
    // 8 lanes per row, 8 experts per lane; reductions = 3 x shfl_xor {1,2,4}.
    const float* L0 = (const float*)lds;
    const float* L1 = L0 + LGT_FLOATS;
    const int row_local = wave * 8 + (lane >> 3);
    const int eb = (lane & 7) * 8;
    const int base = row_local * LGT_STRIDE + eb;

    float v0, v1, v2, v3, v4, v5, v6, v7;
    {
        float4 u0 = *(const float4*)(L0 + base);
        float4 u1 = *(const float4*)(L0 + base + 4);
        float4 w0 = *(const float4*)(L1 + base);
        float4 w1 = *(const float4*)(L1 + base + 4);
        float4 c0 = *(const float4*)(bias + eb);
        float4 c1 = *(const float4*)(bias + eb + 4);
        v0 = u0.x + w0.x + 0.5f * c0.x;
        v1 = u0.y + w0.y + 0.5f * c0.y;
        v2 = u0.z + w0.z + 0.5f * c0.z;
        v3 = u0.w + w0.w + 0.5f * c0.w;
        v4 = u1.x + w1.x + 0.5f * c1.x;
        v5 = u1.y + w1.y + 0.5f * c1.y;
        v6 = u1.z + w1.z + 0.5f * c1.z;
        v7 = u1.w + w1.w + 0.5f * c1.w;
    }

    float m = fmaxf(fmaxf(fmaxf(v0, v1), fmaxf(v2, v3)),
                    fmaxf(fmaxf(v4, v5), fmaxf(v6, v7)));
    m = fmaxf(m, __shfl_xor(m, 1, 64));
    m = fmaxf(m, __shfl_xor(m, 2, 64));
    m = fmaxf(m, __shfl_xor(m, 4, 64));

    float tau_lo = m - 1.0f;
    float tau_hi = m - 0.000244140625f;   // (1/64)^(1/(alpha-1)) = (1/64)^2
    float dm = tau_hi - tau_lo;

    float s0, d;
    d = fmaxf(v0 - tau_lo, 0.f); s0 = d * d;
    d = fmaxf(v1 - tau_lo, 0.f); s0 = fmaf(d, d, s0);
    d = fmaxf(v2 - tau_lo, 0.f); s0 = fmaf(d, d, s0);
    d = fmaxf(v3 - tau_lo, 0.f); s0 = fmaf(d, d, s0);
    d = fmaxf(v4 - tau_lo, 0.f); s0 = fmaf(d, d, s0);
    d = fmaxf(v5 - tau_lo, 0.f); s0 = fmaf(d, d, s0);
    d = fmaxf(v6 - tau_lo, 0.f); s0 = fmaf(d, d, s0);
    d = fmaxf(v7 - tau_lo, 0.f); s0 = fmaf(d, d, s0);
    s0 += __shfl_xor(s0, 1, 64);
    s0 += __shfl_xor(s0, 2, 64);
    s0 += __shfl_xor(s0, 4, 64);
    const float f_lo = s0 - 1.0f;   // fixed for all iterations (as in reference)

    float tau_m = tau_lo, fsum = 1.0f;
#pragma unroll 1
    for (int it = 0; it < 25; ++it) {
        dm *= 0.5f;
        tau_m = tau_lo + dm;
        float s;
        d = fmaxf(v0 - tau_m, 0.f); s = d * d;
        d = fmaxf(v1 - tau_m, 0.f); s = fmaf(d, d, s);
        d = fmaxf(v2 - tau_m, 0.f); s = fmaf(d, d, s);
        d = fmaxf(v3 - tau_m, 0.f); s = fmaf(d, d, s);
        d = fmaxf(v4 - tau_m, 0.f); s = fmaf(d, d, s);
        d = fmaxf(v5 - tau_m, 0.f); s = fmaf(d, d, s);
        d = fmaxf(v6 - tau_m, 0.f); s = fmaf(d, d, s);
        d = fmaxf(v7 - tau_m, 0.f); s = fmaf(d, d, s);
        s += __shfl_xor(s, 1, 64);
        s += __shfl_xor(s, 2, 64);
        s += __shfl_xor(s, 4, 64);
        if ((s - 1.0f) * f_lo >= 0.0f) tau_lo = tau_m;
        fsum = s;
    }
    // p at last midpoint, renormalized by its own sum (ensure_sum_one)
    float rinv = 1.0f / fsum;
    float4 o0, o1;
    d = fmaxf(v0 - tau_m, 0.f); o0.x = d * d * rinv;
    d = fmaxf(v1 - tau_m, 0.f); o0.y = d * d * rinv;
    d = fmaxf(v2 - tau_m, 0.f); o0.z = d * d * rinv;
    d = fmaxf(v3 - tau_m, 0.f); o0.w = d * d * rinv;
    d = fmaxf(v4 - tau_m, 0.f); o1.x = d * d * rinv;
    d = fmaxf(v5 - tau_m, 0.f); o1.y = d * d * rinv;
    d = fmaxf(v6 - tau_m, 0.f); o1.z = d * d * rinv;
    d = fmaxf(v7 - tau_m, 0.f); o1.w = d * d * rinv;

    float* op = out + (size_t)(rowbase + row_local) * N_EXP + eb;
    *(float4*)(op)     = o0;
    *(float4*)(op + 4) = o1;
}

// ---------------------------------------------------------------------------
extern "C" void kernel_launch(void* const* d_in, const int* in_sizes, int n_in,
                              void* d_out, int out_size, void* d_ws, size_t ws_size,
                              hipStream_t stream) {
    (void)n_in; (void)out_size; (void)ws_size;
    const float* x  = (const float*)d_in[0];   // [T, 2048]
    const float* W  = (const float*)d_in[1];   // [64, 2048]
    const float* b  = (const float*)d_in[2];   // [64]
    float* out      = (float*)d_out;           // [T, 64]
    uint8_t* wsimg  = (uint8_t*)d_ws;          // 256 KB W fragment image

    const int T = in_sizes[0] / N_EMBED;       // 32768

    convert_w_kernel<<<dim3(256), dim3(64), 0, stream>>>(W, wsimg);
    router_kernel<<<dim3(T / 64), dim3(512), 0, stream>>>(x, wsimg, b, out);
}

// Round 15
// 65.014 us; speedup vs baseline: 1.0190x; 1.0081x over previous
//
#include <hip/hip_runtime.h>
#include <hip/hip_bf16.h>
#include <stdint.h>

typedef _Float16 half8 __attribute__((ext_vector_type(8)));
typedef float    f32x4 __attribute__((ext_vector_type(4)));

#define N_EMBED   2048
#define N_EXP     64
#define KCHUNK    64
#define NKC       (N_EMBED / KCHUNK)   // 32
#define GCH       16                   // chunks per K-group (K-split 2)
#define TILEB     8192                 // bytes per k-chunk fp16 image
#define LGT_STRIDE 68                  // floats, padded row stride for logit LDS
#define LGT_FLOATS (64 * LGT_STRIDE)   // 4352 floats = 17408 B per region

// ---------------------------------------------------------------------------
// Prelude: W [64][2048] fp32 -> pre-swizzled fp16 image in ws (256 KB).
// Folds the 0.5 = (alpha-1)/temperature scale into W.
// Chunk kc at kc*8192; element (e,dd) at byte ((e*128 + dd*2) ^ ((e&7)<<4)).
// ---------------------------------------------------------------------------
__global__ __launch_bounds__(64) void convert_w_kernel(
        const float* __restrict__ W, uint8_t* __restrict__ wsimg) {
    int tid = blockIdx.x * 64 + threadIdx.x;    // 16384 threads total
    int e   = tid >> 8;                          // expert 0..63
    int d0  = (tid & 255) * 8;                   // 8 consecutive d
    int kc  = d0 >> 6;
    int dd0 = d0 & 63;
    const float* src = W + e * N_EMBED + d0;
    float4 f0 = *(const float4*)(src);
    float4 f1 = *(const float4*)(src + 4);
    float v[8] = {f0.x, f0.y, f0.z, f0.w, f1.x, f1.y, f1.z, f1.w};
    union { _Float16 h[8]; uint4 u; } hv;
#pragma unroll
    for (int j = 0; j < 8; ++j) hv.h[j] = (_Float16)(0.5f * v[j]);
    uint32_t off = (uint32_t)((e * 128 + dd0 * 2) ^ ((e & 7) << 4));
    *(uint4*)(wsimg + (size_t)kc * TILEB + off) = hv.u;
}

// ---------------------------------------------------------------------------
// Main fused kernel (R8 structure; x loads = device-scope sc1, L2-bypass):
//   512 blocks x 512 threads; 8 waves = 2 K-groups x 4 row-quads; 2 blocks/CU.
//   W: ring-4 LDS per group (pair double-buffer), BK=128, 8 rounds; stage
//   pair p+1 at round-p start (4 gload_lds). A: ONE named-register pair set,
//   loaded via inline-asm `global_load_dwordx4 ... sc1` — device scope means
//   the zero-reuse x stream misses L1/L2 by design and is served by L3,
//   leaving the 256 KB W image L2-resident (its 128 MB re-staging becomes
//   L2-local, off the fabric). asm loads are waitcnt-invisible to the
//   compiler, so ALL A-consume waits are explicit (vmcnt(4)+sched_barrier
//   before cvt; vmcnt(8) end-of-round retires the W stage only).
// ---------------------------------------------------------------------------
__device__ __forceinline__ half8 cvt8(f32x4 p, f32x4 q) {
    half8 h;
    h[0] = (_Float16)p[0]; h[1] = (_Float16)p[1];
    h[2] = (_Float16)p[2]; h[3] = (_Float16)p[3];
    h[4] = (_Float16)q[0]; h[5] = (_Float16)q[1];
    h[6] = (_Float16)q[2]; h[7] = (_Float16)q[3];
    return h;
}

__global__ __launch_bounds__(512, 4) void router_kernel(
        const float* __restrict__ x, const uint8_t* __restrict__ img,
        const float* __restrict__ bias, float* __restrict__ out) {
    __shared__ uint8_t lds[65536];   // 2 groups x 4 slots x 8 KB; logits overlay

    const int tid  = threadIdx.x;
    const int wave = tid >> 6;
    const int lane = tid & 63;
    const int l15  = lane & 15;
    const int l4   = lane >> 4;
    const int g    = wave >> 2;        // K-group
    const int q    = wave & 3;         // row quad
    const int rowbase = blockIdx.x * 64;
    const float* xrow = x + (size_t)(rowbase + q * 16 + l15) * N_EMBED
                          + g * (GCH * KCHUNK) + l4 * 8;
    uint8_t* gring = lds + g * (4 * TILEB);

    // LDS byte offsets of B fragments: tile t, k-step s
    uint32_t boff[4][2];
#pragma unroll
    for (int t = 0; t < 4; ++t)
#pragma unroll
        for (int s = 0; s < 2; ++s)
            boff[t][s] = (uint32_t)(((16 * t + l15) * 128 + s * 64 + l4 * 16)
                                    ^ ((l15 & 7) << 4));

    f32x4 acc[4];
#pragma unroll
    for (int t = 0; t < 4; ++t) acc[t] = (f32x4){0.f, 0.f, 0.f, 0.f};

    // Staging: thread-group tg (256 threads) stages its group's chunks.
    const int tg  = tid >> 8;
    const int t8  = tid & 255;
    auto STAGE2 = [&](int p) {   // stage chunks 2p, 2p+1 (4 gload_lds/thread? 2 each -> 4 total)
#pragma unroll
        for (int c = 0; c < 2; ++c) {
            int kc = 2 * p + c;
            const uint8_t* gsrc = img + (size_t)(tg * GCH + kc) * TILEB;
            uint8_t* dst = lds + tg * (4 * TILEB) + (kc & 3) * TILEB;
            __builtin_amdgcn_global_load_lds(
                (const __attribute__((address_space(1))) void*)(gsrc + t8 * 16),
                (__attribute__((address_space(3))) void*)(dst + t8 * 16),
                16, 0, 0);
            __builtin_amdgcn_global_load_lds(
                (const __attribute__((address_space(1))) void*)(gsrc + 4096 + t8 * 16),
                (__attribute__((address_space(3))) void*)(dst + 4096 + t8 * 16),
                16, 0, 0);
        }
    };

    f32x4 A0, A1, A2, A3, A4, A5, A6, A7;    // one pair set, named regs only
    auto LOADA2 = [&](int p) {               // pair p: 8 x dwordx4, sc1 (L2-bypass)
        const float* ap = xrow + 2 * p * KCHUNK;
        asm volatile("global_load_dwordx4 %0, %1, off sc1"            : "=v"(A0) : "v"(ap));
        asm volatile("global_load_dwordx4 %0, %1, off offset:16 sc1"  : "=v"(A1) : "v"(ap));
        asm volatile("global_load_dwordx4 %0, %1, off offset:128 sc1" : "=v"(A2) : "v"(ap));
        asm volatile("global_load_dwordx4 %0, %1, off offset:144 sc1" : "=v"(A3) : "v"(ap));
        asm volatile("global_load_dwordx4 %0, %1, off offset:256 sc1" : "=v"(A4) : "v"(ap));
        asm volatile("global_load_dwordx4 %0, %1, off offset:272 sc1" : "=v"(A5) : "v"(ap));
        asm volatile("global_load_dwordx4 %0, %1, off offset:384 sc1" : "=v"(A6) : "v"(ap));
        asm volatile("global_load_dwordx4 %0, %1, off offset:400 sc1" : "=v"(A7) : "v"(ap));
    };
    auto MFMAS2 = [&](int p, half8 a0, half8 a1, half8 a2, half8 a3) {
        const uint8_t* lb0 = gring + (size_t)((2 * p) & 3) * TILEB;
        const uint8_t* lb1 = gring + (size_t)((2 * p + 1) & 3) * TILEB;
#pragma unroll
        for (int t = 0; t < 4; ++t) {
            half8 bh = *(const half8*)(lb0 + boff[t][0]);
            acc[t] = __builtin_amdgcn_mfma_f32_16x16x32_f16(a0, bh, acc[t], 0, 0, 0);
        }
#pragma unroll
        for (int t = 0; t < 4; ++t) {
            half8 bh = *(const half8*)(lb0 + boff[t][1]);
            acc[t] = __builtin_amdgcn_mfma_f32_16x16x32_f16(a1, bh, acc[t], 0, 0, 0);
        }
#pragma unroll
        for (int t = 0; t < 4; ++t) {
            half8 bh = *(const half8*)(lb1 + boff[t][0]);
            acc[t] = __builtin_amdgcn_mfma_f32_16x16x32_f16(a2, bh, acc[t], 0, 0, 0);
        }
#pragma unroll
        for (int t = 0; t < 4; ++t) {
            half8 bh = *(const half8*)(lb1 + boff[t][1]);
            acc[t] = __builtin_amdgcn_mfma_f32_16x16x32_f16(a3, bh, acc[t], 0, 0, 0);
        }
    };

    // ---- prologue: stage pair 0 (4 ops); A(0) x8 (asm) ----
    STAGE2(0);
    __builtin_amdgcn_sched_barrier(0);
    LOADA2(0);
    __builtin_amdgcn_sched_barrier(0);
    // queue: [S(0)x4, A(0)x8] -> vmcnt(8) retires S(0); A(0) in flight
    asm volatile("s_waitcnt vmcnt(8)" ::: "memory");
    __builtin_amdgcn_s_barrier();
    __builtin_amdgcn_sched_barrier(0);

    // ---- rounds 0..6 (uniform) ----
#pragma unroll 1
    for (int p = 0; p < 7; ++p) {
        // entry queue: [A(p)x8]
        STAGE2(p + 1);                       // -> [A(p)x8, S(p+1)x4]
        __builtin_amdgcn_sched_barrier(0);
        asm volatile("s_waitcnt vmcnt(4)" ::: "memory");   // A(p) done; S in flight
        __builtin_amdgcn_sched_barrier(0);
        {
            half8 a0 = cvt8(A0, A1);
            half8 a1 = cvt8(A2, A3);
            half8 a2 = cvt8(A4, A5);
            half8 a3 = cvt8(A6, A7);
            __builtin_amdgcn_sched_barrier(0);
            LOADA2(p + 1);                   // -> [S(p+1)x4, A(p+1)x8]
            __builtin_amdgcn_sched_barrier(0);
            MFMAS2(p, a0, a1, a2, a3);
        }
        // vmcnt(8) retires the W stage; A(p+1) stays in flight. lgkmcnt(0):
        // this wave's LDS reads of the slots being re-staged next round done.
        asm volatile("s_waitcnt vmcnt(8) lgkmcnt(0)" ::: "memory");
        __builtin_amdgcn_s_barrier();
        __builtin_amdgcn_sched_barrier(0);
    }

    // ---- round 7 (tail): consume A(7), slots {2,3} ----
    asm volatile("s_waitcnt vmcnt(0)" ::: "memory");       // A(7) done
    __builtin_amdgcn_sched_barrier(0);
    {
        half8 a0 = cvt8(A0, A1);
        half8 a1 = cvt8(A2, A3);
        half8 a2 = cvt8(A4, A5);
        half8 a3 = cvt8(A6, A7);
        MFMAS2(7, a0, a1, a2, a3);
    }

    // ---- combine K-halves via LDS (overlay on W ring) ----
    __syncthreads();
    {
        float* lgt = (float*)lds + g * LGT_FLOATS;
#pragma unroll
        for (int t = 0; t < 4; ++t)
#pragma unroll
            for (int r = 0; r < 4; ++r)
                lgt[(q * 16 + l4 * 4 + r) * LGT_STRIDE + t * 16 + l15] = acc[t][r];
    }
    __syncthreads();

    // ---------------- entmax-1.5 epilogue ----------------
    // 8 lanes per row, 8 experts per lane; reductions = 3 x shfl_xor {1,2,4}.
    const float* L0 = (const float*)lds;
    const float* L1 = L0 + LGT_FLOATS;
    const int row_local = wave * 8 + (lane >> 3);
    const int eb = (lane & 7) * 8;
    const int base = row_local * LGT_STRIDE + eb;

    float v0, v1, v2, v3, v4, v5, v6, v7;
    {
        float4 u0 = *(const float4*)(L0 + base);
        float4 u1 = *(const float4*)(L0 + base + 4);
        float4 w0 = *(const float4*)(L1 + base);
        float4 w1 = *(const float4*)(L1 + base + 4);
        float4 c0 = *(const float4*)(bias + eb);
        float4 c1 = *(const float4*)(bias + eb + 4);
        v0 = u0.x + w0.x + 0.5f * c0.x;
        v1 = u0.y + w0.y + 0.5f * c0.y;
        v2 = u0.z + w0.z + 0.5f * c0.z;
        v3 = u0.w + w0.w + 0.5f * c0.w;
        v4 = u1.x + w1.x + 0.5f * c1.x;
        v5 = u1.y + w1.y + 0.5f * c1.y;
        v6 = u1.z + w1.z + 0.5f * c1.z;
        v7 = u1.w + w1.w + 0.5f * c1.w;
    }

    float m = fmaxf(fmaxf(fmaxf(v0, v1), fmaxf(v2, v3)),
                    fmaxf(fmaxf(v4, v5), fmaxf(v6, v7)));
    m = fmaxf(m, __shfl_xor(m, 1, 64));
    m = fmaxf(m, __shfl_xor(m, 2, 64));
    m = fmaxf(m, __shfl_xor(m, 4, 64));

    float tau_lo = m - 1.0f;
    float tau_hi = m - 0.000244140625f;   // (1/64)^(1/(alpha-1)) = (1/64)^2
    float dm = tau_hi - tau_lo;

    float s0, d;
    d = fmaxf(v0 - tau_lo, 0.f); s0 = d * d;
    d = fmaxf(v1 - tau_lo, 0.f); s0 = fmaf(d, d, s0);
    d = fmaxf(v2 - tau_lo, 0.f); s0 = fmaf(d, d, s0);
    d = fmaxf(v3 - tau_lo, 0.f); s0 = fmaf(d, d, s0);
    d = fmaxf(v4 - tau_lo, 0.f); s0 = fmaf(d, d, s0);
    d = fmaxf(v5 - tau_lo, 0.f); s0 = fmaf(d, d, s0);
    d = fmaxf(v6 - tau_lo, 0.f); s0 = fmaf(d, d, s0);
    d = fmaxf(v7 - tau_lo, 0.f); s0 = fmaf(d, d, s0);
    s0 += __shfl_xor(s0, 1, 64);
    s0 += __shfl_xor(s0, 2, 64);
    s0 += __shfl_xor(s0, 4, 64);
    const float f_lo = s0 - 1.0f;   // fixed for all iterations (as in reference)

    float tau_m = tau_lo, fsum = 1.0f;
#pragma unroll 1
    for (int it = 0; it < 25; ++it) {
        dm *= 0.5f;
        tau_m = tau_lo + dm;
        float s;
        d = fmaxf(v0 - tau_m, 0.f); s = d * d;
        d = fmaxf(v1 - tau_m, 0.f); s = fmaf(d, d, s);
        d = fmaxf(v2 - tau_m, 0.f); s = fmaf(d, d, s);
        d = fmaxf(v3 - tau_m, 0.f); s = fmaf(d, d, s);
        d = fmaxf(v4 - tau_m, 0.f); s = fmaf(d, d, s);
        d = fmaxf(v5 - tau_m, 0.f); s = fmaf(d, d, s);
        d = fmaxf(v6 - tau_m, 0.f); s = fmaf(d, d, s);
        d = fmaxf(v7 - tau_m, 0.f); s = fmaf(d, d, s);
        s += __shfl_xor(s, 1, 64);
        s += __shfl_xor(s, 2, 64);
        s += __shfl_xor(s, 4, 64);
        if ((s - 1.0f) * f_lo >= 0.0f) tau_lo = tau_m;
        fsum = s;
    }
    // p at last midpoint, renormalized by its own sum (ensure_sum_one)
    float rinv = 1.0f / fsum;
    float4 o0, o1;
    d = fmaxf(v0 - tau_m, 0.f); o0.x = d * d * rinv;
    d = fmaxf(v1 - tau_m, 0.f); o0.y = d * d * rinv;
    d = fmaxf(v2 - tau_m, 0.f); o0.z = d * d * rinv;
    d = fmaxf(v3 - tau_m, 0.f); o0.w = d * d * rinv;
    d = fmaxf(v4 - tau_m, 0.f); o1.x = d * d * rinv;
    d = fmaxf(v5 - tau_m, 0.f); o1.y = d * d * rinv;
    d = fmaxf(v6 - tau_m, 0.f); o1.z = d * d * rinv;
    d = fmaxf(v7 - tau_m, 0.f); o1.w = d * d * rinv;

    float* op = out + (size_t)(rowbase + row_local) * N_EXP + eb;
    *(float4*)(op)     = o0;
    *(float4*)(op + 4) = o1;
}

// ---------------------------------------------------------------------------
extern "C" void kernel_launch(void* const* d_in, const int* in_sizes, int n_in,
                              void* d_out, int out_size, void* d_ws, size_t ws_size,
                              hipStream_t stream) {
    (void)n_in; (void)out_size; (void)ws_size;
    const float* x  = (const float*)d_in[0];   // [T, 2048]
    const float* W  = (const float*)d_in[1];   // [64, 2048]
    const float* b  = (const float*)d_in[2];   // [64]
    float* out      = (float*)d_out;           // [T, 64]
    uint8_t* wsimg  = (uint8_t*)d_ws;          // 256 KB W fp16 image

    const int T = in_sizes[0] / N_EMBED;       // 32768

    convert_w_kernel<<<dim3(256), dim3(64), 0, stream>>>(W, wsimg);
    router_kernel<<<dim3(T / 64), dim3(512), 0, stream>>>(x, wsimg, b, out);
}

// Round 16
// 59.889 us; speedup vs baseline: 1.1062x; 1.0856x over previous
//
#include <hip/hip_runtime.h>
#include <hip/hip_bf16.h>
#include <stdint.h>

typedef _Float16 half8 __attribute__((ext_vector_type(8)));
typedef float    f32x4 __attribute__((ext_vector_type(4)));

#define N_EMBED   2048
#define N_EXP     64
#define KCHUNK    64
#define NKC       (N_EMBED / KCHUNK)   // 32
#define GCH       16                   // chunks per K-group (K-split 2)
#define TILEB     8192                 // bytes per k-chunk fp16 image
#define LGT_STRIDE 68                  // floats, padded row stride for logit LDS
#define LGT_FLOATS (64 * LGT_STRIDE)   // 4352 floats = 17408 B per region

// ---------------------------------------------------------------------------
// Prelude: W [64][2048] fp32 -> pre-swizzled fp16 image in ws (256 KB).
// Folds the 0.5 = (alpha-1)/temperature scale into W.
// Chunk kc at kc*8192; element (e,dd) at byte ((e*128 + dd*2) ^ ((e&7)<<4)).
// ---------------------------------------------------------------------------
__global__ __launch_bounds__(256) void convert_w_kernel(
        const float* __restrict__ W, uint8_t* __restrict__ wsimg) {
    int tid = blockIdx.x * 256 + threadIdx.x;   // 16384 threads total
    int e   = tid >> 8;                          // expert 0..63
    int d0  = (tid & 255) * 8;                   // 8 consecutive d
    int kc  = d0 >> 6;
    int dd0 = d0 & 63;
    const float* src = W + e * N_EMBED + d0;
    float4 f0 = *(const float4*)(src);
    float4 f1 = *(const float4*)(src + 4);
    float v[8] = {f0.x, f0.y, f0.z, f0.w, f1.x, f1.y, f1.z, f1.w};
    union { _Float16 h[8]; uint4 u; } hv;
#pragma unroll
    for (int j = 0; j < 8; ++j) hv.h[j] = (_Float16)(0.5f * v[j]);
    uint32_t off = (uint32_t)((e * 128 + dd0 * 2) ^ ((e & 7) << 4));
    *(uint4*)(wsimg + (size_t)kc * TILEB + off) = hv.u;
}

// ---------------------------------------------------------------------------
// Main fused kernel (R8 — empirical optimum, restored):
//   512 blocks x 512 threads; 8 waves = 2 K-groups x 4 row-quads; 2 blocks/CU.
//   W: ring-4 LDS per group (pair double-buffer), BK=128, 8 rounds; stage
//   pair p+1 at round-p start. A: ONE named-register pair set, consume (cvt)
//   then reload pair p+1. End-of-round wait vmcnt(8) retires the W stage
//   only; A stays in flight. Raw s_barrier. All hot state in named registers.
// ---------------------------------------------------------------------------
__device__ __forceinline__ half8 cvt8(f32x4 p, f32x4 q) {
    half8 h;
    h[0] = (_Float16)p[0]; h[1] = (_Float16)p[1];
    h[2] = (_Float16)p[2]; h[3] = (_Float16)p[3];
    h[4] = (_Float16)q[0]; h[5] = (_Float16)q[1];
    h[6] = (_Float16)q[2]; h[7] = (_Float16)q[3];
    return h;
}

__global__ __launch_bounds__(512, 4) void router_kernel(
        const float* __restrict__ x, const uint8_t* __restrict__ img,
        const float* __restrict__ bias, float* __restrict__ out) {
    __shared__ uint8_t lds[65536];   // 2 groups x 4 slots x 8 KB; logits overlay

    const int tid  = threadIdx.x;
    const int wave = tid >> 6;
    const int lane = tid & 63;
    const int l15  = lane & 15;
    const int l4   = lane >> 4;
    const int g    = wave >> 2;        // K-group
    const int q    = wave & 3;         // row quad
    const int rowbase = blockIdx.x * 64;
    const float* xrow = x + (size_t)(rowbase + q * 16 + l15) * N_EMBED
                          + g * (GCH * KCHUNK) + l4 * 8;
    uint8_t* gring = lds + g * (4 * TILEB);

    // LDS byte offsets of B fragments: tile t, k-step s
    uint32_t boff[4][2];
#pragma unroll
    for (int t = 0; t < 4; ++t)
#pragma unroll
        for (int s = 0; s < 2; ++s)
            boff[t][s] = (uint32_t)(((16 * t + l15) * 128 + s * 64 + l4 * 16)
                                    ^ ((l15 & 7) << 4));

    f32x4 acc[4];
#pragma unroll
    for (int t = 0; t < 4; ++t) acc[t] = (f32x4){0.f, 0.f, 0.f, 0.f};

    // Staging: thread-group tg (256 threads) stages its group's chunks.
    const int tg  = tid >> 8;
    const int t8  = tid & 255;
    auto STAGE2 = [&](int p) {   // stage chunks 2p, 2p+1 (4 gload_lds/thread)
#pragma unroll
        for (int c = 0; c < 2; ++c) {
            int kc = 2 * p + c;
            const uint8_t* gsrc = img + (size_t)(tg * GCH + kc) * TILEB;
            uint8_t* dst = lds + tg * (4 * TILEB) + (kc & 3) * TILEB;
#pragma unroll
            for (int j = 0; j < 2; ++j) {
                __builtin_amdgcn_global_load_lds(
                    (const __attribute__((address_space(1))) void*)(gsrc + j * 4096 + t8 * 16),
                    (__attribute__((address_space(3))) void*)(dst + j * 4096 + t8 * 16),
                    16, 0, 0);
            }
        }
    };

    f32x4 A0, A1, A2, A3, A4, A5, A6, A7;    // one pair set, named regs only
    auto LOADA2 = [&](int p) {               // pair p: 8 x dwordx4
        const float* ap = xrow + 2 * p * KCHUNK;
        A0 = *(const f32x4*)(ap);
        A1 = *(const f32x4*)(ap + 4);
        A2 = *(const f32x4*)(ap + 32);
        A3 = *(const f32x4*)(ap + 36);
        A4 = *(const f32x4*)(ap + 64);
        A5 = *(const f32x4*)(ap + 68);
        A6 = *(const f32x4*)(ap + 96);
        A7 = *(const f32x4*)(ap + 100);
    };
    auto MFMAS2 = [&](int p, half8 a0, half8 a1, half8 a2, half8 a3) {
        const uint8_t* lb0 = gring + (size_t)((2 * p) & 3) * TILEB;
        const uint8_t* lb1 = gring + (size_t)((2 * p + 1) & 3) * TILEB;
#pragma unroll
        for (int t = 0; t < 4; ++t) {
            half8 bh = *(const half8*)(lb0 + boff[t][0]);
            acc[t] = __builtin_amdgcn_mfma_f32_16x16x32_f16(a0, bh, acc[t], 0, 0, 0);
        }
#pragma unroll
        for (int t = 0; t < 4; ++t) {
            half8 bh = *(const half8*)(lb0 + boff[t][1]);
            acc[t] = __builtin_amdgcn_mfma_f32_16x16x32_f16(a1, bh, acc[t], 0, 0, 0);
        }
#pragma unroll
        for (int t = 0; t < 4; ++t) {
            half8 bh = *(const half8*)(lb1 + boff[t][0]);
            acc[t] = __builtin_amdgcn_mfma_f32_16x16x32_f16(a2, bh, acc[t], 0, 0, 0);
        }
#pragma unroll
        for (int t = 0; t < 4; ++t) {
            half8 bh = *(const half8*)(lb1 + boff[t][1]);
            acc[t] = __builtin_amdgcn_mfma_f32_16x16x32_f16(a3, bh, acc[t], 0, 0, 0);
        }
    };

    // ---- prologue: stage pair 0; load A pair 0 ----
    STAGE2(0);
    __builtin_amdgcn_sched_barrier(0);
    LOADA2(0);
    __builtin_amdgcn_sched_barrier(0);
    asm volatile("s_waitcnt vmcnt(8)" ::: "memory");   // S(0) done; A(0) in flight
    __builtin_amdgcn_s_barrier();
    __builtin_amdgcn_sched_barrier(0);

    // ---- rounds 0..6 (uniform) ----
#pragma unroll 1
    for (int p = 0; p < 7; ++p) {
        STAGE2(p + 1);
        __builtin_amdgcn_sched_barrier(0);
        {
            // cvt consumes A(p) (compiler inserts the vmcnt for the dep),
            // then the same registers are refilled with pair p+1.
            half8 a0 = cvt8(A0, A1);
            half8 a1 = cvt8(A2, A3);
            half8 a2 = cvt8(A4, A5);
            half8 a3 = cvt8(A6, A7);
            LOADA2(p + 1);
            MFMAS2(p, a0, a1, a2, a3);
        }
        // S(p+1)[4] is older than A(p+1)[8]: vmcnt(8) completes the W stage,
        // leaves the A pair in flight. lgkmcnt(0): my LDS reads of the slots
        // being re-staged next round are done before crossing the barrier.
        asm volatile("s_waitcnt vmcnt(8) lgkmcnt(0)" ::: "memory");
        __builtin_amdgcn_s_barrier();
        __builtin_amdgcn_sched_barrier(0);
    }

    // ---- round 7 (tail): consume A(7), slots {2,3} ----
    {
        half8 a0 = cvt8(A0, A1);
        half8 a1 = cvt8(A2, A3);
        half8 a2 = cvt8(A4, A5);
        half8 a3 = cvt8(A6, A7);
        MFMAS2(7, a0, a1, a2, a3);
    }

    // ---- combine K-halves via LDS (overlay on W ring) ----
    __syncthreads();
    {
        float* lgt = (float*)lds + g * LGT_FLOATS;
#pragma unroll
        for (int t = 0; t < 4; ++t)
#pragma unroll
            for (int r = 0; r < 4; ++r)
                lgt[(q * 16 + l4 * 4 + r) * LGT_STRIDE + t * 16 + l15] = acc[t][r];
    }
    __syncthreads();

    // ---------------- entmax-1.5 epilogue ----------------
    // 8 lanes per row, 8 experts per lane; reductions = 3 x shfl_xor {1,2,4}.
    const float* L0 = (const float*)lds;
    const float* L1 = L0 + LGT_FLOATS;
    const int row_local = wave * 8 + (lane >> 3);
    const int eb = (lane & 7) * 8;
    const int base = row_local * LGT_STRIDE + eb;

    float v0, v1, v2, v3, v4, v5, v6, v7;
    {
        float4 u0 = *(const float4*)(L0 + base);
        float4 u1 = *(const float4*)(L0 + base + 4);
        float4 w0 = *(const float4*)(L1 + base);
        float4 w1 = *(const float4*)(L1 + base + 4);
        float4 c0 = *(const float4*)(bias + eb);
        float4 c1 = *(const float4*)(bias + eb + 4);
        v0 = u0.x + w0.x + 0.5f * c0.x;
        v1 = u0.y + w0.y + 0.5f * c0.y;
        v2 = u0.z + w0.z + 0.5f * c0.z;
        v3 = u0.w + w0.w + 0.5f * c0.w;
        v4 = u1.x + w1.x + 0.5f * c1.x;
        v5 = u1.y + w1.y + 0.5f * c1.y;
        v6 = u1.z + w1.z + 0.5f * c1.z;
        v7 = u1.w + w1.w + 0.5f * c1.w;
    }

    float m = fmaxf(fmaxf(fmaxf(v0, v1), fmaxf(v2, v3)),
                    fmaxf(fmaxf(v4, v5), fmaxf(v6, v7)));
    m = fmaxf(m, __shfl_xor(m, 1, 64));
    m = fmaxf(m, __shfl_xor(m, 2, 64));
    m = fmaxf(m, __shfl_xor(m, 4, 64));

    float tau_lo = m - 1.0f;
    float tau_hi = m - 0.000244140625f;   // (1/64)^(1/(alpha-1)) = (1/64)^2
    float dm = tau_hi - tau_lo;

    float s0;
    {
        float d;
        d = fmaxf(v0 - tau_lo, 0.f); s0 = d * d;
        d = fmaxf(v1 - tau_lo, 0.f); s0 = fmaf(d, d, s0);
        d = fmaxf(v2 - tau_lo, 0.f); s0 = fmaf(d, d, s0);
        d = fmaxf(v3 - tau_lo, 0.f); s0 = fmaf(d, d, s0);
        d = fmaxf(v4 - tau_lo, 0.f); s0 = fmaf(d, d, s0);
        d = fmaxf(v5 - tau_lo, 0.f); s0 = fmaf(d, d, s0);
        d = fmaxf(v6 - tau_lo, 0.f); s0 = fmaf(d, d, s0);
        d = fmaxf(v7 - tau_lo, 0.f); s0 = fmaf(d, d, s0);
    }
    s0 += __shfl_xor(s0, 1, 64);
    s0 += __shfl_xor(s0, 2, 64);
    s0 += __shfl_xor(s0, 4, 64);
    const float f_lo = s0 - 1.0f;   // fixed for all iterations (as in reference)

    float tau_m = tau_lo, fsum = 1.0f;
#pragma unroll 1
    for (int it = 0; it < 25; ++it) {
        dm *= 0.5f;
        tau_m = tau_lo + dm;
        float s, d;
        d = fmaxf(v0 - tau_m, 0.f); s = d * d;
        d = fmaxf(v1 - tau_m, 0.f); s = fmaf(d, d, s);
        d = fmaxf(v2 - tau_m, 0.f); s = fmaf(d, d, s);
        d = fmaxf(v3 - tau_m, 0.f); s = fmaf(d, d, s);
        d = fmaxf(v4 - tau_m, 0.f); s = fmaf(d, d, s);
        d = fmaxf(v5 - tau_m, 0.f); s = fmaf(d, d, s);
        d = fmaxf(v6 - tau_m, 0.f); s = fmaf(d, d, s);
        d = fmaxf(v7 - tau_m, 0.f); s = fmaf(d, d, s);
        s += __shfl_xor(s, 1, 64);
        s += __shfl_xor(s, 2, 64);
        s += __shfl_xor(s, 4, 64);
        if ((s - 1.0f) * f_lo >= 0.0f) tau_lo = tau_m;
        fsum = s;
    }
    // p at last midpoint, renormalized by its own sum (ensure_sum_one)
    float rinv = 1.0f / fsum;
    float4 o0, o1;
    {
        float d;
        d = fmaxf(v0 - tau_m, 0.f); o0.x = d * d * rinv;
        d = fmaxf(v1 - tau_m, 0.f); o0.y = d * d * rinv;
        d = fmaxf(v2 - tau_m, 0.f); o0.z = d * d * rinv;
        d = fmaxf(v3 - tau_m, 0.f); o0.w = d * d * rinv;
        d = fmaxf(v4 - tau_m, 0.f); o1.x = d * d * rinv;
        d = fmaxf(v5 - tau_m, 0.f); o1.y = d * d * rinv;
        d = fmaxf(v6 - tau_m, 0.f); o1.z = d * d * rinv;
        d = fmaxf(v7 - tau_m, 0.f); o1.w = d * d * rinv;
    }
    float* op = out + (size_t)(rowbase + row_local) * N_EXP + eb;
    *(float4*)(op)     = o0;
    *(float4*)(op + 4) = o1;
}

// ---------------------------------------------------------------------------
extern "C" void kernel_launch(void* const* d_in, const int* in_sizes, int n_in,
                              void* d_out, int out_size, void* d_ws, size_t ws_size,
                              hipStream_t stream) {
    (void)n_in; (void)out_size; (void)ws_size;
    const float* x  = (const float*)d_in[0];   // [T, 2048]
    const float* W  = (const float*)d_in[1];   // [64, 2048]
    const float* b  = (const float*)d_in[2];   // [64]
    float* out      = (float*)d_out;           // [T, 64]
    uint8_t* wsimg  = (uint8_t*)d_ws;          // 256 KB W fp16 image

    const int T = in_sizes[0] / N_EMBED;       // 32768

    convert_w_kernel<<<dim3(64), dim3(256), 0, stream>>>(W, wsimg);
    router_kernel<<<dim3(T / 64), dim3(512), 0, stream>>>(x, wsimg, b, out);
}